// Round 11
// baseline (103.744 us; speedup 1.0000x reference)
//
#include <hip/hip_runtime.h>

#define NL 133
#define HT 60
#define WD 108
#define PIX (HT*WD)          // 6480
#define CT 432               // 3*12*12 channels after unfold
#define L45 45               // patches
#define STR 440              // LDS row stride in halves (880B)
#define BTC 4
#define NB (BTC*NL)          // 532
#define EPIX (3*PIX)         // 19440

typedef _Float16 f16;
typedef _Float16 h4v __attribute__((ext_vector_type(4)));
typedef _Float16 h8v __attribute__((ext_vector_type(8)));
typedef float f32x4 __attribute__((ext_vector_type(4)));

__device__ __forceinline__ f32x4 mfma_k32(h8v a, h8v b, f32x4 c){
  return __builtin_amdgcn_mfma_f32_16x16x32_f16(a, b, c, 0, 0, 0);
}
__device__ __forceinline__ f32x4 mfma_k16(h4v a, h4v b, f32x4 c){
  return __builtin_amdgcn_mfma_f32_16x16x16f16(a, b, c, 0, 0, 0);
}

// ---- kprep: blocks [0,408): S transpose+unfold -> Su[b][pa*144+kr]
//      blocks [408,588): IMu/IKu[bt][pa][c] = unfold(I*M), unfold(I*(1-M)) f16
__global__ __launch_bounds__(256) void kprep(const float* __restrict__ S,
                                             const float* __restrict__ I,
                                             const float* __restrict__ M,
                                             f16* __restrict__ Su,
                                             f16* __restrict__ IMu,
                                             f16* __restrict__ IKu){
  __shared__ float tile[64][135];
  int blk = blockIdx.x;
  int tid = threadIdx.x;
  if (blk < BTC*102){
    int bt = blk / 102, t = blk % 102;
    int pix0 = t * 64;
    // Load: 64*133 = 8512 contiguous floats, 16B-aligned. 2128 float4.
    int npx = PIX - pix0; if (npx > 64) npx = 64;   // 64 or 16 (both mult of 4)
    int nval = npx * NL;
    const float* Sflat = &S[((size_t)bt*PIX + pix0)*NL];
    for (int f4 = tid; f4 < 2128; f4 += 256){
      int f = f4*4;
      if (f < nval){
        float4 v = *(const float4*)&Sflat[f];
        int p0 = (f  ) / NL, n0 = (f  ) - p0*NL;
        int p1 = (f+1) / NL, n1 = (f+1) - p1*NL;
        int p2 = (f+2) / NL, n2 = (f+2) - p2*NL;
        int p3 = (f+3) / NL, n3 = (f+3) - p3*NL;
        tile[p0][n0] = v.x;
        tile[p1][n1] = v.y;
        tile[p2][n2] = v.z;
        tile[p3][n3] = v.w;
      }
    }
    __syncthreads();
    // Store: 4 consecutive pixels per thread. pix 4-aligned => same row (108%4==0),
    // same patch & ky (kx in {0,4,8}), kr 4-aligned => 8B-aligned h4v store.
    for (int w4 = tid; w4 < NL*16; w4 += 256){
      int nn = w4 >> 4, pp = (w4 & 15)*4;
      int pix = pix0 + pp;
      if (pp < npx){
        int y = pix / WD, x = pix - y*WD;      // x multiple of 4
        int py = y/12, ky = y%12, px = x/12, kx = x - (x/12)*12;
        int pa = py*9 + px, kr = ky*12 + kx;
        h4v v;
        v[0] = (f16)tile[pp  ][nn];
        v[1] = (f16)tile[pp+1][nn];
        v[2] = (f16)tile[pp+2][nn];
        v[3] = (f16)tile[pp+3][nn];
        *(h4v*)&Su[(size_t)(bt*NL + nn)*PIX + pa*144 + kr] = v;
      }
    }
  } else {
    int b2 = blk - BTC*102;            // (bt, patch)
    int bt = b2 / L45, pa = b2 % L45;
    int py = pa/9, px = pa%9;
    const float* Ib = I + (size_t)bt*EPIX;
    const float* Mb = M + (size_t)bt*PIX;
    // 4 channels per thread: c 4-aligned => same ch & ky, kx in {0,4,8},
    // pix 4-aligned => float4 loads legal; h4v stores 8B-aligned.
    for (int c4 = tid; c4 < 108; c4 += 256){
      int c = c4*4;
      int ch = c/144, kr = c - ch*144;
      int ky = kr/12, kx = kr - ky*12;
      int pix = (py*12 + ky)*WD + px*12 + kx;
      float4 iv = *(const float4*)&Ib[ch*PIX + pix];
      float4 mv = *(const float4*)&Mb[pix];
      h4v um, uk;
      um[0] = (f16)(iv.x*mv.x); uk[0] = (f16)(iv.x*(1.f-mv.x));
      um[1] = (f16)(iv.y*mv.y); uk[1] = (f16)(iv.y*(1.f-mv.y));
      um[2] = (f16)(iv.z*mv.z); uk[2] = (f16)(iv.z*(1.f-mv.z));
      um[3] = (f16)(iv.w*mv.w); uk[3] = (f16)(iv.w*(1.f-mv.w));
      *(h4v*)&IMu[((size_t)bt*L45 + pa)*CT + c] = um;
      *(h4v*)&IKu[((size_t)bt*L45 + pa)*CT + c] = uk;
    }
  }
}

// ---- kmain (round-10 verbatim) ----
template<bool USE_SCR>
__global__ __launch_bounds__(256) void kmain(const f16* __restrict__ IMu,
                                             const f16* __restrict__ IKu,
                                             const f16* __restrict__ Su,
                                             f16* __restrict__ scr,
                                             float* __restrict__ outAcc){
  __shared__ f16 lds[(L45 + 48)*STR];           // 81,840 B -> 2 blocks/CU
  f16* bufU = lds;
  f16* bufK = lds + L45*STR;

  int b  = blockIdx.x;
  int bt = b / NL;
  int tid = threadIdx.x;

  // zero bufK rows 45..47 (K-tail contracts against zeros)
  for (int z = tid; z < 3*STR; z += 256) bufK[L45*STR + z] = (f16)0.f;

  // Phase A: bufU[p][c] = IMu[p][c]*Su[p][c%144]; bufK[p][c] = IKu[p][c]*Su[...]
  {
    const f16* IMb = IMu + (size_t)bt*L45*CT;
    const f16* IKb = IKu + (size_t)bt*L45*CT;
    const f16* Sb  = Su  + (size_t)b*PIX;
    for (int slot = tid; slot < L45*54; slot += 256){
      int p = slot / 54, cg = slot % 54;
      int c0 = cg*8;
      h8v im = *(const h8v*)&IMb[p*CT + c0];
      h8v ik = *(const h8v*)&IKb[p*CT + c0];
      h8v sv = *(const h8v*)&Sb[p*144 + (c0 % 144)];
      *(h8v*)&bufU[p*STR + c0] = im*sv;
      *(h8v*)&bufK[p*STR + c0] = ik*sv;
    }
  }
  __syncthreads();

  // ---- GEMM1: Wm(p,q) = sum_c U(p,c)*Kt(q,c).  9 16x16 tiles, 3 slots/wave.
  int wid  = tid >> 6;
  int lane = tid & 63;
  int lrow = lane & 15, lgrp = lane >> 4;

  f32x4 acc0 = {0.f,0.f,0.f,0.f}, acc1 = acc0, acc2 = acc0;
  int t0 = wid;
  int t1 = wid + 4;
  int t2 = (wid + 8 < 9) ? wid + 8 : 8;
  int ti0 = t0/3, tj0 = t0%3;
  int ti1 = t1/3, tj1 = t1%3;
  int ti2 = t2/3, tj2 = t2%3;

  const f16* uA0 = &bufU[(ti0*16 + lrow)*STR];
  const f16* uA1 = &bufU[(ti1*16 + lrow)*STR];
  const f16* uA2 = &bufU[(ti2*16 + lrow)*STR];
  const f16* kB0 = &bufK[(tj0*16 + lrow)*STR];
  const f16* kB1 = &bufK[(tj1*16 + lrow)*STR];
  const f16* kB2 = &bufK[(tj2*16 + lrow)*STR];

  for (int ks = 0; ks < 13; ++ks){
    int c0 = ks*32 + lgrp*8;
    h8v a0 = *(const h8v*)&uA0[c0];
    h8v a1 = *(const h8v*)&uA1[c0];
    h8v a2 = *(const h8v*)&uA2[c0];
    h8v b0 = *(const h8v*)&kB0[c0];
    h8v b1 = *(const h8v*)&kB1[c0];
    h8v b2 = *(const h8v*)&kB2[c0];
    acc0 = mfma_k32(a0, b0, acc0);
    acc1 = mfma_k32(a1, b1, acc1);
    acc2 = mfma_k32(a2, b2, acc2);
  }
  { // K-tail c in [416,432)
    int c0 = 416 + lgrp*4;
    h4v a0 = *(const h4v*)&uA0[c0];
    h4v a1 = *(const h4v*)&uA1[c0];
    h4v a2 = *(const h4v*)&uA2[c0];
    h4v b0 = *(const h4v*)&kB0[c0];
    h4v b1 = *(const h4v*)&kB1[c0];
    h4v b2 = *(const h4v*)&kB2[c0];
    acc0 = mfma_k16(a0, b0, acc0);
    acc1 = mfma_k16(a1, b1, acc1);
    acc2 = mfma_k16(a2, b2, acc2);
  }
  __syncthreads();

  // ---- stage raw Wm (f32) + normalized Wm (f16) over dead bufU
  float* Wm32 = (float*)lds;                       // [48][49]
  f16*   Wm16 = (f16*)((char*)lds + 48*49*4);      // [48][48]
  {
    #pragma unroll
    for (int r = 0; r < 4; ++r){
      Wm32[(ti0*16 + lgrp*4 + r)*49 + tj0*16 + lrow] = acc0[r];
      Wm32[(ti1*16 + lgrp*4 + r)*49 + tj1*16 + lrow] = acc1[r];
      Wm32[(ti2*16 + lgrp*4 + r)*49 + tj2*16 + lrow] = acc2[r];
    }
  }
  __syncthreads();

  // ---- L1 normalize: 4 threads per row (rows 0..44).
  {
    int row = tid >> 2, part = tid & 3;
    if (row < L45){
      int j0 = part*12;
      float rs = 0.f;
      for (int q = j0; q < j0+12; ++q) rs += fabsf(Wm32[row*49 + q]);
      rs += __shfl_xor(rs, 1);
      rs += __shfl_xor(rs, 2);
      float inv = 1.0f / fmaxf(rs, 1e-12f);
      for (int j = j0; j < j0+12; ++j)
        Wm16[row*48 + j] = (j < L45) ? (f16)(Wm32[row*49 + j]*inv) : (f16)0.f;
    }
  }
  __syncthreads();

  // ---- GEMM2: D(i,c) = sum_j Wm(i,j)*Kt(j,c). 3 i-tiles x 27 c-tiles.
  h8v aw0 = *(const h8v*)&Wm16[( 0 + lrow)*48 + lgrp*8];
  h8v aw1 = *(const h8v*)&Wm16[(16 + lrow)*48 + lgrp*8];
  h8v aw2 = *(const h8v*)&Wm16[(32 + lrow)*48 + lgrp*8];
  h4v at0 = *(const h4v*)&Wm16[( 0 + lrow)*48 + 32 + lgrp*4];
  h4v at1 = *(const h4v*)&Wm16[(16 + lrow)*48 + 32 + lgrp*4];
  h4v at2 = *(const h4v*)&Wm16[(32 + lrow)*48 + 32 + lgrp*4];

  if (USE_SCR) __syncthreads();   // frags now in regs; Dl may clobber Wm region

  f16* Dl = lds;                  // D[i][c] at lds[i*432+c], max 19439 < bufK@19800

  for (int cb = wid; cb < 27; cb += 4){
    int cbase = cb*16 + lrow;
    h8v bK; h4v bT;
    #pragma unroll
    for (int r = 0; r < 8; ++r) bK[r] = bufK[(lgrp*8 + r)*STR + cbase];
    #pragma unroll
    for (int r = 0; r < 4; ++r) bT[r] = bufK[(32 + lgrp*4 + r)*STR + cbase];

    int ch  = cb / 9;
    int kr  = (cb % 9)*16 + lrow;
    int ky  = kr / 12, kx = kr - ky*12;
    int pixc = ch*PIX + ky*WD + kx;

    f32x4 d0 = {0.f,0.f,0.f,0.f}, d1 = d0, d2 = d0;
    d0 = mfma_k32(aw0, bK, d0);  d0 = mfma_k16(at0, bT, d0);
    d1 = mfma_k32(aw1, bK, d1);  d1 = mfma_k16(at1, bT, d1);
    d2 = mfma_k32(aw2, bK, d2);  d2 = mfma_k16(at2, bT, d2);

    #pragma unroll
    for (int r = 0; r < 4; ++r){
      { int i = 0 + lgrp*4 + r;
        if (USE_SCR) Dl[i*CT + cbase] = (f16)d0[r];
        else {
          int iy = i/9, ix = i - iy*9;
          atomicAdd(&outAcc[(size_t)bt*EPIX + pixc + (iy*12)*WD + ix*12], (float)d0[r]); } }
      { int i = 16 + lgrp*4 + r;
        if (USE_SCR) Dl[i*CT + cbase] = (f16)d1[r];
        else {
          int iy = i/9, ix = i - iy*9;
          atomicAdd(&outAcc[(size_t)bt*EPIX + pixc + (iy*12)*WD + ix*12], (float)d1[r]); } }
      { int i = 32 + lgrp*4 + r;
        if (i < L45){
          if (USE_SCR) Dl[i*CT + cbase] = (f16)d2[r];
          else {
            int iy = i/9, ix = i - iy*9;
            atomicAdd(&outAcc[(size_t)bt*EPIX + pixc + (iy*12)*WD + ix*12], (float)d2[r]); } } }
    }
  }

  if (USE_SCR){
    __syncthreads();             // all D staged
    f16* sb = scr + (size_t)b*L45*CT;
    for (int slot = tid; slot < L45*54; slot += 256){
      h8v v = *(const h8v*)&Dl[slot*8];
      *(h8v*)&sb[slot*8] = v;    // fully coalesced 16B stores
    }
  }
}

// ---- kreduce: 16 sub-threads per float4-group over 133 layers, blend, scatter
__global__ __launch_bounds__(256) void kreduce(const float* __restrict__ I,
                                               const float* __restrict__ M,
                                               const f16* __restrict__ scr,
                                               float* __restrict__ out){
  int t = blockIdx.x*256 + threadIdx.x;
  int sub = t & 15, g = t >> 4;
  if (g >= BTC*L45*108) return;
  int bt = g / (L45*108), rem = g % (L45*108);
  int pa = rem / 108, c4 = rem % 108;
  int c0 = c4*4;
  const f16* p = scr + ((size_t)(bt*NL)*L45 + pa)*CT + c0;
  f32x4 a = {0.f,0.f,0.f,0.f};
  #pragma unroll
  for (int k = 0; k < 9; ++k){
    int nn = sub + k*16;
    int nc = nn < NL ? nn : NL-1;
    h4v v = *(const h4v*)&p[(size_t)nc*L45*CT];
    if (nn < NL){
      a[0] += (float)v[0]; a[1] += (float)v[1];
      a[2] += (float)v[2]; a[3] += (float)v[3];
    }
  }
  #pragma unroll
  for (int s = 1; s < 16; s <<= 1){
    a[0] += __shfl_xor(a[0], s); a[1] += __shfl_xor(a[1], s);
    a[2] += __shfl_xor(a[2], s); a[3] += __shfl_xor(a[3], s);
  }
  if (sub == 0){
    int ch = c0/144, kr = c0%144, ky = kr/12, kx = kr%12;
    int py = pa/9, px = pa%9;
    int pix = (py*12 + ky)*WD + px*12 + kx;
    size_t io = (size_t)bt*EPIX + ch*PIX + pix;
    float4 iv = *(const float4*)&I[io];
    float4 mv = *(const float4*)&M[(size_t)bt*PIX + pix];
    float4 o;
    o.x = iv.x*(1.f-mv.x) + a[0]*mv.x;
    o.y = iv.y*(1.f-mv.y) + a[1]*mv.y;
    o.z = iv.z*(1.f-mv.z) + a[2]*mv.z;
    o.w = iv.w*(1.f-mv.w) + a[3]*mv.w;
    *(float4*)&out[io] = o;
  }
}

__global__ __launch_bounds__(256) void kfinal(const float* __restrict__ I,
                                              const float* __restrict__ M,
                                              float* __restrict__ out){
  int g = blockIdx.x*256 + threadIdx.x;
  if (g >= BTC*EPIX) return;
  int bt = g / EPIX, e = g % EPIX;
  float a = out[g];
  float m = M[bt*PIX + (e % PIX)];
  out[g] = I[g]*(1.f - m) + a*m;
}

extern "C" void kernel_launch(void* const* d_in, const int* in_sizes, int n_in,
                              void* d_out, int out_size, void* d_ws, size_t ws_size,
                              hipStream_t stream){
  const float* I = (const float*)d_in[0];
  const float* S = (const float*)d_in[1];
  const float* M = (const float*)d_in[2];
  float* out = (float*)d_out;

  const size_t needSu  = (size_t)NB*PIX*sizeof(f16);      //  6,894,720
  const size_t needIM  = (size_t)BTC*L45*CT*sizeof(f16);  //    155,520 each
  const size_t needScr = (size_t)NB*L45*CT*sizeof(f16);   // 20,684,160
  const size_t prepSz  = needSu + 2*needIM;

  f16* Su  = (f16*)d_ws;
  f16* IMu = (f16*)((char*)d_ws + needSu);
  f16* IKu = (f16*)((char*)d_ws + needSu + needIM);
  f16* scr = (f16*)((char*)d_ws + prepSz);
  bool useScr = ws_size >= prepSz + needScr;

  kprep<<<BTC*102 + BTC*L45, 256, 0, stream>>>(S, I, M, Su, IMu, IKu);

  if (useScr){
    kmain<true ><<<NB, 256, 0, stream>>>(IMu, IKu, Su, scr, out);
    kreduce<<<((BTC*L45*108)*16 + 255)/256, 256, 0, stream>>>(I, M, scr, out);
  } else {
    (void)hipMemsetAsync(out, 0, (size_t)BTC*EPIX*sizeof(float), stream);
    kmain<false><<<NB, 256, 0, stream>>>(IMu, IKu, Su, scr, out);
    kfinal<<<(BTC*EPIX + 255)/256, 256, 0, stream>>>(I, M, out);
  }
}